// Round 1
// baseline (351.347 us; speedup 1.0000x reference)
//
#include <hip/hip_runtime.h>

// Problem constants (from reference): B=4, N=2048, IN_F=512, HEADS=8, D=64
#define BB   4
#define NN   2048
#define INF  512
#define HH   8
#define DD   64
#define BH   (BB*HH)   // 32

// ============================================================================
// Algorithm: A[b,h,i,j] = softmax_j( leaky_relu(q_j + k_i) ), H = A @ V.
// exp(leaky(x)) is continuous & piecewise multiplicative:
//   x>=0: e^{q_j} e^{k_i};   x<0: e^{0.01 q_j} e^{0.01 k_i}
// Sort j by q_j per (b,h); then for each i with threshold t=-k_i:
//   num_d = e^{k} * (T1_d - Pref1(pos)_d) + e^{.01k} * Pref2(pos)_d
//   den   = e^{k} * (LT1  - lpref1(pos)) + e^{.01k} * lpref2(pos)
// where pos = #{j: q_j <= t} (upper bound), Pref1 = exclusive prefix of
// e^{q}·V over sorted order, Pref2 likewise with e^{0.01 q}.
// O(N·D) instead of O(N^2·D).
// ============================================================================

// ---------------- Kernel 1: V = X@Wv + bv ; q,k scalar scores ----------------
__global__ __launch_bounds__(256) void k_vqk(
    const float* __restrict__ X, const float* __restrict__ Wv, const float* __restrict__ bv,
    const float* __restrict__ Wq, const float* __restrict__ bq,
    const float* __restrict__ Wk, const float* __restrict__ bk,
    float* __restrict__ V, float* __restrict__ qsg, float* __restrict__ ksg)
{
  __shared__ float Xs[32][128];     // 16 KB c-chunk staging
  __shared__ float Vs[32][DD + 1];  // padded to break bank conflicts in q/k pass
  const int t  = threadIdx.x;
  const int r0 = blockIdx.x * 32;   // 256 blocks x 32 rows = 8192 rows
  const int d2 = t & 31;            // thread owns d2 and d2+32
  const int rg = t >> 5;            // 0..7 -> rows rg*4 .. rg*4+3
  float acc[4][2];
  #pragma unroll
  for (int r = 0; r < 4; r++) { acc[r][0] = 0.f; acc[r][1] = 0.f; }

  for (int cc = 0; cc < INF; cc += 128) {
    __syncthreads();
    {  // stage 32x128 X chunk, coalesced float4
      const int row = t >> 3;
      const int seg = (t & 7) * 16;
      const float4* src = (const float4*)(X + (size_t)(r0 + row) * INF + cc + seg);
      float4 a0 = src[0], a1 = src[1], a2 = src[2], a3 = src[3];
      float4* dst = (float4*)(&Xs[row][seg]);
      dst[0] = a0; dst[1] = a1; dst[2] = a2; dst[3] = a3;
    }
    __syncthreads();
    for (int c4 = 0; c4 < 128; c4 += 4) {
      const float* wp = Wv + (size_t)(cc + c4) * DD + d2;
      const float w00 = wp[0],      w01 = wp[32];
      const float w10 = wp[DD],     w11 = wp[DD + 32];
      const float w20 = wp[2*DD],   w21 = wp[2*DD + 32];
      const float w30 = wp[3*DD],   w31 = wp[3*DD + 32];
      #pragma unroll
      for (int r = 0; r < 4; r++) {
        const float4 x4 = *(const float4*)(&Xs[rg*4 + r][c4]);
        acc[r][0] += x4.x*w00 + x4.y*w10 + x4.z*w20 + x4.w*w30;
        acc[r][1] += x4.x*w01 + x4.y*w11 + x4.z*w21 + x4.w*w31;
      }
    }
  }
  __syncthreads();
  #pragma unroll
  for (int r = 0; r < 4; r++) {
    const int row = rg*4 + r;
    const float a0 = acc[r][0] + bv[d2];
    const float a1 = acc[r][1] + bv[d2 + 32];
    V[(size_t)(r0 + row) * DD + d2]      = a0;
    V[(size_t)(r0 + row) * DD + d2 + 32] = a1;
    Vs[row][d2] = a0;  Vs[row][d2 + 32] = a1;
  }
  __syncthreads();
  // q,k: 32 rows x 8 heads x {q,k} = 512 tasks, 2 per thread
  #pragma unroll
  for (int s = 0; s < 2; s++) {
    const int id  = t*2 + s;
    const int row = id >> 4;
    const int h   = id & 7;
    const bool isK = (id & 8) != 0;
    const float* W = isK ? Wk : Wq;
    float a = isK ? bk[h] : bq[h];
    #pragma unroll 8
    for (int dd = 0; dd < DD; dd++) a += Vs[row][dd] * W[dd*HH + h];
    const int grow = r0 + row;
    const int b = grow >> 11, n = grow & (NN - 1);
    (isK ? ksg : qsg)[(b*HH + h) * NN + n] = a;
  }
}

// ------- Kernel 2: per-(b,h) bitonic sort of q + fp64 prefix scans -----------
__global__ __launch_bounds__(256) void k_sortscan(
    const float* __restrict__ qsg, const float* __restrict__ V,
    float* __restrict__ sq,
    float* __restrict__ P1, float* __restrict__ P2,
    float* __restrict__ off1, float* __restrict__ off2,
    float* __restrict__ l1, float* __restrict__ l2,
    float* __restrict__ loff1, float* __restrict__ loff2)
{
  __shared__ float  key[NN];         // 8 KB
  __shared__ int    idx[NN];         // 8 KB
  __shared__ float  e1s[NN];         // 8 KB
  __shared__ float  e2s[NN];         // 8 KB
  __shared__ double cs1[4][DD];      // 2 KB chunk sums
  __shared__ double cs2[4][DD];      // 2 KB
  __shared__ double sl1[4], sl2[4];
  const int t  = threadIdx.x;
  const int bh = blockIdx.x;

  for (int w = 0; w < 8; w++) { const int i = t + w*256; key[i] = qsg[bh*NN + i]; idx[i] = i; }
  __syncthreads();
  // bitonic sort ascending (key, idx)
  for (int size = 2; size <= NN; size <<= 1) {
    for (int stride = size >> 1; stride > 0; stride >>= 1) {
      for (int w = 0; w < 4; w++) {
        const int p = t + w*256;                               // 1024 pairs
        const int i = ((p & ~(stride - 1)) << 1) | (p & (stride - 1));
        const int j = i + stride;
        const bool up = ((i & size) == 0);
        const float a = key[i], b2 = key[j];
        if (up ? (a > b2) : (a < b2)) {
          key[i] = b2; key[j] = a;
          const int tmp = idx[i]; idx[i] = idx[j]; idx[j] = tmp;
        }
      }
      __syncthreads();
    }
  }
  for (int w = 0; w < 8; w++) {
    const int r = t + w*256;
    const float kv = key[r];
    sq[bh*NN + r] = kv;
    e1s[r] = __expf(kv);
    e2s[r] = __expf(0.01f * kv);
  }
  __syncthreads();
  // 4 chunks of 512: exclusive chunk-local prefixes, fp64 accumulation
  const int d = t & 63;
  const int g = t >> 6;
  const float* Vb  = V  + (size_t)(bh >> 3) * NN * DD;
  float* P1o = P1 + (size_t)bh * NN * DD;
  float* P2o = P2 + (size_t)bh * NN * DD;
  double a1 = 0.0, a2 = 0.0, s1 = 0.0, s2 = 0.0;
  #pragma unroll 4
  for (int rr = 0; rr < 512; rr++) {
    const int r = (g << 9) + rr;
    const int j = idx[r];
    const float v = Vb[(size_t)j * DD + d];
    P1o[(size_t)r * DD + d] = (float)a1;
    P2o[(size_t)r * DD + d] = (float)a2;
    const float e1v = e1s[r], e2v = e2s[r];
    a1 += (double)e1v * (double)v;
    a2 += (double)e2v * (double)v;
    if (d == 0) {
      l1[bh*NN + r] = (float)s1;  l2[bh*NN + r] = (float)s2;
      s1 += e1v;  s2 += e2v;
    }
  }
  cs1[g][d] = a1;  cs2[g][d] = a2;
  if (d == 0) { sl1[g] = s1; sl2[g] = s2; }
  __syncthreads();
  if (t < DD) {   // per-d chunk offsets (index 4 = grand total)
    double o1 = 0.0, o2 = 0.0;
    for (int gg = 0; gg < 4; gg++) {
      off1[((size_t)bh*5 + gg)*DD + t] = (float)o1;
      off2[((size_t)bh*5 + gg)*DD + t] = (float)o2;
      o1 += cs1[gg][t];  o2 += cs2[gg][t];
    }
    off1[((size_t)bh*5 + 4)*DD + t] = (float)o1;
    off2[((size_t)bh*5 + 4)*DD + t] = (float)o2;
  }
  if (t == 0) {
    double p1 = 0.0, p2 = 0.0;
    for (int gg = 0; gg < 4; gg++) {
      loff1[bh*5 + gg] = (float)p1;  loff2[bh*5 + gg] = (float)p2;
      p1 += sl1[gg];  p2 += sl2[gg];
    }
    loff1[bh*5 + 4] = (float)p1;  loff2[bh*5 + 4] = (float)p2;
  }
}

// ---------------- Kernel 3: binary search + combine + write ------------------
__global__ __launch_bounds__(256) void k_out(
    const float* __restrict__ sq, const float* __restrict__ ksg,
    const float* __restrict__ P1, const float* __restrict__ P2,
    const float* __restrict__ off1, const float* __restrict__ off2,
    const float* __restrict__ l1, const float* __restrict__ l2,
    const float* __restrict__ loff1, const float* __restrict__ loff2,
    float* __restrict__ out)
{
  const int t  = threadIdx.x;
  const int bh = blockIdx.x >> 9;                       // 32 bh x 512 i-blocks
  const int i  = ((blockIdx.x & 511) << 2) + (t >> 6);  // 4 i per block, 1 per wave
  const int d  = t & 63;
  const int b  = bh >> 3, h = bh & 7;
  const float kv = ksg[bh*NN + i];
  const float tt = -kv;
  // upper_bound over sorted q (all lanes identical -> broadcast loads, L1-hot)
  const float* s = sq + bh*NN;
  int lo = 0, hi = NN;
  while (lo < hi) { const int mid = (lo + hi) >> 1; if (s[mid] <= tt) lo = mid + 1; else hi = mid; }
  const int pos = lo;
  const float ek  = __expf(kv);
  const float ek2 = __expf(0.01f * kv);
  const size_t base = (size_t)bh * NN * DD;
  const float T1  = off1[((size_t)bh*5 + 4)*DD + d];
  const float Lt1 = loff1[bh*5 + 4];
  float p1v, p2v, q1v, q2v;
  if (pos < NN) {      // wave-uniform branch (pos identical across lanes)
    const int ch = pos >> 9;
    p1v = P1[base + (size_t)pos*DD + d] + off1[((size_t)bh*5 + ch)*DD + d];
    p2v = P2[base + (size_t)pos*DD + d] + off2[((size_t)bh*5 + ch)*DD + d];
    q1v = l1[bh*NN + pos] + loff1[bh*5 + ch];
    q2v = l2[bh*NN + pos] + loff2[bh*5 + ch];
  } else {
    p1v = T1;                            p2v = off2[((size_t)bh*5 + 4)*DD + d];
    q1v = Lt1;                           q2v = loff2[bh*5 + 4];
  }
  const float num = ek * (T1 - p1v)  + ek2 * p2v;
  const float den = ek * (Lt1 - q1v) + ek2 * q2v;
  out[((size_t)(b*NN + i)) * (HH*DD) + h*DD + d] = num / den;
}

extern "C" void kernel_launch(void* const* d_in, const int* in_sizes, int n_in,
                              void* d_out, int out_size, void* d_ws, size_t ws_size,
                              hipStream_t stream)
{
  (void)in_sizes; (void)n_in; (void)out_size; (void)ws_size;
  const float* X  = (const float*)d_in[0];
  const float* Wv = (const float*)d_in[1];
  const float* bv = (const float*)d_in[2];
  const float* Wq = (const float*)d_in[3];
  const float* bq = (const float*)d_in[4];
  const float* Wk = (const float*)d_in[5];
  const float* bk = (const float*)d_in[6];
  float* out = (float*)d_out;

  // workspace carve-up (~37.2 MB of floats)
  float* w = (float*)d_ws;
  float* V     = w;  w += (size_t)BB*NN*DD;   // 524288
  float* qsg   = w;  w += BH*NN;              // 65536
  float* ksg   = w;  w += BH*NN;
  float* sq    = w;  w += BH*NN;
  float* l1    = w;  w += BH*NN;
  float* l2    = w;  w += BH*NN;
  float* loff1 = w;  w += BH*5;
  float* loff2 = w;  w += BH*5;
  float* off1  = w;  w += BH*5*DD;
  float* off2  = w;  w += BH*5*DD;
  float* P1    = w;  w += (size_t)BH*NN*DD;   // 4194304
  float* P2    = w;  w += (size_t)BH*NN*DD;

  k_vqk<<<256, 256, 0, stream>>>(X, Wv, bv, Wq, bq, Wk, bk, V, qsg, ksg);
  k_sortscan<<<BH, 256, 0, stream>>>(qsg, V, sq, P1, P2, off1, off2, l1, l2, loff1, loff2);
  k_out<<<BH*512, 256, 0, stream>>>(sq, ksg, P1, P2, off1, off2, l1, l2, loff1, loff2, out);
}

// Round 2
// 181.214 us; speedup vs baseline: 1.9388x; 1.9388x over previous
//
#include <hip/hip_runtime.h>

// Problem constants (from reference): B=4, N=2048, IN_F=512, HEADS=8, D=64
#define BB   4
#define NN   2048
#define INF  512
#define HH   8
#define DD   64
#define BH   (BB*HH)   // 32
#define NCK  8         // 256-row chunks per (b,h)

// ============================================================================
// A[b,h,i,j] = softmax_j( leaky_relu(q_j + k_i) ), H = A @ V.
// exp(leaky(x)) is continuous & piecewise multiplicative:
//   x>=0: e^{q_j} e^{k_i};   x<0: e^{0.01 q_j} e^{0.01 k_i}
// Sort j by q_j per (b,h); prefix sums of e^{q} V and e^{0.01 q} V in sorted
// order turn each output row into: binary search + 2 prefix lookups. O(N·D).
// Round 2: hierarchical scan (was serial per bh -> 207us @1.4% occupancy).
// ============================================================================

// ---------------- Kernel 1: V = X@Wv + bv ; q,k scalar scores ----------------
__global__ __launch_bounds__(256) void k_vqk(
    const float* __restrict__ X, const float* __restrict__ Wv, const float* __restrict__ bv,
    const float* __restrict__ Wq, const float* __restrict__ bq,
    const float* __restrict__ Wk, const float* __restrict__ bk,
    float* __restrict__ V, float* __restrict__ qsg, float* __restrict__ ksg)
{
  __shared__ float Xs[32][128];     // 16 KB c-chunk staging
  __shared__ float Vs[32][DD + 1];  // padded
  const int t  = threadIdx.x;
  const int r0 = blockIdx.x * 32;
  const int d2 = t & 31;
  const int rg = t >> 5;
  float acc[4][2];
  #pragma unroll
  for (int r = 0; r < 4; r++) { acc[r][0] = 0.f; acc[r][1] = 0.f; }

  for (int cc = 0; cc < INF; cc += 128) {
    __syncthreads();
    {
      const int row = t >> 3;
      const int seg = (t & 7) * 16;
      const float4* src = (const float4*)(X + (size_t)(r0 + row) * INF + cc + seg);
      float4 a0 = src[0], a1 = src[1], a2 = src[2], a3 = src[3];
      float4* dst = (float4*)(&Xs[row][seg]);
      dst[0] = a0; dst[1] = a1; dst[2] = a2; dst[3] = a3;
    }
    __syncthreads();
    for (int c4 = 0; c4 < 128; c4 += 4) {
      const float* wp = Wv + (size_t)(cc + c4) * DD + d2;
      const float w00 = wp[0],      w01 = wp[32];
      const float w10 = wp[DD],     w11 = wp[DD + 32];
      const float w20 = wp[2*DD],   w21 = wp[2*DD + 32];
      const float w30 = wp[3*DD],   w31 = wp[3*DD + 32];
      #pragma unroll
      for (int r = 0; r < 4; r++) {
        const float4 x4 = *(const float4*)(&Xs[rg*4 + r][c4]);
        acc[r][0] += x4.x*w00 + x4.y*w10 + x4.z*w20 + x4.w*w30;
        acc[r][1] += x4.x*w01 + x4.y*w11 + x4.z*w21 + x4.w*w31;
      }
    }
  }
  __syncthreads();
  #pragma unroll
  for (int r = 0; r < 4; r++) {
    const int row = rg*4 + r;
    const float a0 = acc[r][0] + bv[d2];
    const float a1 = acc[r][1] + bv[d2 + 32];
    V[(size_t)(r0 + row) * DD + d2]      = a0;
    V[(size_t)(r0 + row) * DD + d2 + 32] = a1;
    Vs[row][d2] = a0;  Vs[row][d2 + 32] = a1;
  }
  __syncthreads();
  #pragma unroll
  for (int s = 0; s < 2; s++) {
    const int id  = t*2 + s;
    const int row = id >> 4;
    const int h   = id & 7;
    const bool isK = (id & 8) != 0;
    const float* W = isK ? Wk : Wq;
    float a = isK ? bk[h] : bq[h];
    #pragma unroll 8
    for (int dd = 0; dd < DD; dd++) a += Vs[row][dd] * W[dd*HH + h];
    const int grow = r0 + row;
    const int b = grow >> 11, n = grow & (NN - 1);
    (isK ? ksg : qsg)[(b*HH + h) * NN + n] = a;
  }
}

// ---------------- Kernel 2: bitonic sort of q per (b,h), in-place ------------
__global__ __launch_bounds__(1024) void k_sort(
    float* __restrict__ q, unsigned short* __restrict__ idxg)
{
  __shared__ float key[NN];   // 8 KB
  __shared__ int   idx[NN];   // 8 KB
  const int t  = threadIdx.x;
  const int bh = blockIdx.x;
  key[t]        = q[bh*NN + t];        idx[t]        = t;
  key[t + 1024] = q[bh*NN + t + 1024]; idx[t + 1024] = t + 1024;
  __syncthreads();
  for (int size = 2; size <= NN; size <<= 1) {
    for (int stride = size >> 1; stride > 0; stride >>= 1) {
      const int i = ((t & ~(stride - 1)) << 1) | (t & (stride - 1));
      const int j = i + stride;
      const bool up = ((i & size) == 0);
      const float a = key[i], b = key[j];
      if (up ? (a > b) : (a < b)) {
        key[i] = b; key[j] = a;
        const int tmp = idx[i]; idx[i] = idx[j]; idx[j] = tmp;
      }
      __syncthreads();
    }
  }
  q[bh*NN + t]        = key[t];
  q[bh*NN + t + 1024] = key[t + 1024];
  idxg[bh*NN + t]        = (unsigned short)idx[t];
  idxg[bh*NN + t + 1024] = (unsigned short)idx[t + 1024];
}

// -------- Kernel 3: hierarchical scan — chunk-local prefixes + chunk sums ----
// grid: 32 bh x 8 chunks of 256 rows; 256 thr: d=t&63, g=t>>6 owns 64 rows.
__global__ __launch_bounds__(256) void k_scan(
    const float* __restrict__ sq, const unsigned short* __restrict__ idxg,
    const float* __restrict__ V,
    float* __restrict__ P1, float* __restrict__ P2,
    float* __restrict__ l1, float* __restrict__ l2,
    float* __restrict__ S1g, float* __restrict__ S2g,
    float* __restrict__ SL1, float* __restrict__ SL2)
{
  __shared__ float ss1[4][64], ss2[4][64], sl1[4], sl2[4];
  const int t  = threadIdx.x;
  const int bh = blockIdx.x >> 3;
  const int ck = blockIdx.x & 7;
  const int d  = t & 63, g = t >> 6;
  const int r0 = ck*256 + g*64;
  const float* Vb  = V + (size_t)(bh >> 3) * NN * DD;
  const float* sqb = sq + bh*NN;
  const unsigned short* ib = idxg + bh*NN;
  float a1 = 0.f, a2 = 0.f, s1 = 0.f, s2 = 0.f;
  #pragma unroll 4
  for (int rr = 0; rr < 64; rr++) {
    const int r = r0 + rr;
    const float qv = sqb[r];
    const float e1 = __expf(qv), e2 = __expf(0.01f*qv);
    const float v  = Vb[(size_t)ib[r]*DD + d];
    a1 += e1*v;  a2 += e2*v;  s1 += e1;  s2 += e2;
  }
  ss1[g][d] = a1;  ss2[g][d] = a2;
  if (d == 0) { sl1[g] = s1;  sl2[g] = s2; }
  __syncthreads();
  float o1 = 0.f, o2 = 0.f, lo1 = 0.f, lo2 = 0.f;
  for (int gg = 0; gg < g; gg++) { o1 += ss1[gg][d]; o2 += ss2[gg][d]; lo1 += sl1[gg]; lo2 += sl2[gg]; }
  if (g == 0) {   // chunk totals -> scratch (lives in d_out, dead before k_out)
    S1g[(bh*NCK + ck)*64 + d] = ss1[0][d]+ss1[1][d]+ss1[2][d]+ss1[3][d];
    S2g[(bh*NCK + ck)*64 + d] = ss2[0][d]+ss2[1][d]+ss2[2][d]+ss2[3][d];
    if (d == 0) {
      SL1[bh*NCK + ck] = sl1[0]+sl1[1]+sl1[2]+sl1[3];
      SL2[bh*NCK + ck] = sl2[0]+sl2[1]+sl2[2]+sl2[3];
    }
  }
  // pass 2: store exclusive chunk-local prefixes (V re-load is L2-hot)
  a1 = o1; a2 = o2; s1 = lo1; s2 = lo2;
  float* P1b = P1 + (size_t)bh*NN*DD;
  float* P2b = P2 + (size_t)bh*NN*DD;
  #pragma unroll 4
  for (int rr = 0; rr < 64; rr++) {
    const int r = r0 + rr;
    const float qv = sqb[r];
    const float e1 = __expf(qv), e2 = __expf(0.01f*qv);
    const float v  = Vb[(size_t)ib[r]*DD + d];
    P1b[(size_t)r*DD + d] = a1;
    P2b[(size_t)r*DD + d] = a2;
    if (d == 0) { l1[bh*NN + r] = s1;  l2[bh*NN + r] = s2; }
    a1 += e1*v;  a2 += e2*v;  s1 += e1;  s2 += e2;
  }
}

// ---------- Kernel 4: fp64 scan of the 8 chunk sums -> chunk offsets ---------
__global__ __launch_bounds__(256) void k_off(
    const float* __restrict__ S1g, const float* __restrict__ S2g,
    const float* __restrict__ SL1, const float* __restrict__ SL2,
    float* __restrict__ Off1, float* __restrict__ Off2,
    float* __restrict__ Loff1, float* __restrict__ Loff2)
{
  const int bh = blockIdx.x;
  const int t  = threadIdx.x;
  if (t < 128) {
    const int d = t & 63;
    const bool h2 = t >= 64;
    const float* S = h2 ? S2g : S1g;
    float* O = h2 ? Off2 : Off1;
    double a = 0.0;
    for (int ck = 0; ck < NCK; ck++) {
      O[((size_t)bh*(NCK+1) + ck)*64 + d] = (float)a;
      a += (double)S[((size_t)bh*NCK + ck)*64 + d];
    }
    O[((size_t)bh*(NCK+1) + NCK)*64 + d] = (float)a;
  } else if (t == 128 || t == 129) {
    const bool h2 = (t == 129);
    const float* S = h2 ? SL2 : SL1;
    float* O = h2 ? Loff2 : Loff1;
    double a = 0.0;
    for (int ck = 0; ck < NCK; ck++) { O[bh*(NCK+1) + ck] = (float)a; a += (double)S[bh*NCK + ck]; }
    O[bh*(NCK+1) + NCK] = (float)a;
  }
}

// ------- Kernel 5: 64-ary search (2 rounds) + combine + write ----------------
__global__ __launch_bounds__(256) void k_out(
    const float* __restrict__ sq, const float* __restrict__ ksg,
    const float* __restrict__ P1, const float* __restrict__ P2,
    const float* __restrict__ Off1, const float* __restrict__ Off2,
    const float* __restrict__ l1, const float* __restrict__ l2,
    const float* __restrict__ Loff1, const float* __restrict__ Loff2,
    float* __restrict__ out)
{
  const int t  = threadIdx.x;
  const int bh = blockIdx.x >> 9;
  const int i  = ((blockIdx.x & 511) << 2) + (t >> 6);
  const int d  = t & 63;                      // == lane id within wave
  const int b  = bh >> 3, h = bh & 7;
  const float kv = ksg[bh*NN + i];
  const float tt = -kv;
  const float* s = sq + bh*NN;
  // round 1: lane d probes block-of-32 boundary; sorted => ballot contiguous
  const unsigned long long m1 = __ballot(s[d*32 + 31] <= tt);
  const int c1 = __popcll(m1);
  int pos;
  if (c1 == 64) pos = NN;
  else {
    const int bs = c1 << 5;
    const unsigned long long m2 = __ballot(s[bs + (d & 31)] <= tt);
    pos = bs + (__popcll(m2) >> 1);   // both wave halves probe identically
  }
  const float ek  = __expf(kv);
  const float ek2 = __expf(0.01f * kv);
  const size_t base = (size_t)bh * NN * DD;
  const float T1  = Off1[((size_t)bh*(NCK+1) + NCK)*64 + d];
  const float Lt1 = Loff1[bh*(NCK+1) + NCK];
  float p1v, p2v, q1v, q2v;
  if (pos < NN) {   // wave-uniform
    const int ch = pos >> 8;
    p1v = P1[base + (size_t)pos*DD + d] + Off1[((size_t)bh*(NCK+1) + ch)*64 + d];
    p2v = P2[base + (size_t)pos*DD + d] + Off2[((size_t)bh*(NCK+1) + ch)*64 + d];
    q1v = l1[bh*NN + pos] + Loff1[bh*(NCK+1) + ch];
    q2v = l2[bh*NN + pos] + Loff2[bh*(NCK+1) + ch];
  } else {
    p1v = T1;   p2v = Off2[((size_t)bh*(NCK+1) + NCK)*64 + d];
    q1v = Lt1;  q2v = Loff2[bh*(NCK+1) + NCK];
  }
  const float num = ek * (T1 - p1v)  + ek2 * p2v;
  const float den = ek * (Lt1 - q1v) + ek2 * q2v;
  out[((size_t)(b*NN + i)) * (HH*DD) + h*DD + d] = num / den;
}

extern "C" void kernel_launch(void* const* d_in, const int* in_sizes, int n_in,
                              void* d_out, int out_size, void* d_ws, size_t ws_size,
                              hipStream_t stream)
{
  (void)in_sizes; (void)n_in; (void)out_size; (void)ws_size;
  const float* X  = (const float*)d_in[0];
  const float* Wv = (const float*)d_in[1];
  const float* bv = (const float*)d_in[2];
  const float* Wq = (const float*)d_in[3];
  const float* bq = (const float*)d_in[4];
  const float* Wk = (const float*)d_in[5];
  const float* bk = (const float*)d_in[6];
  float* out = (float*)d_out;

  // workspace carve-up (36.98 MB, <= round-1's proven 37.05 MB)
  float* w = (float*)d_ws;
  float* V     = w;  w += (size_t)BB*NN*DD;        // 524288
  float* qsg   = w;  w += BH*NN;                   // sorted in-place -> sq
  float* ksg   = w;  w += BH*NN;
  float* l1    = w;  w += BH*NN;
  float* l2    = w;  w += BH*NN;
  unsigned short* idxg = (unsigned short*)w;  w += BH*NN/2;   // ushort
  float* Off1  = w;  w += BH*(NCK+1)*DD;           // 18432
  float* Off2  = w;  w += BH*(NCK+1)*DD;
  float* Loff1 = w;  w += BH*(NCK+1);
  float* Loff2 = w;  w += BH*(NCK+1);
  float* P1    = w;  w += (size_t)BH*NN*DD;        // 4194304
  float* P2    = w;  w += (size_t)BH*NN*DD;

  // chunk-sum scratch lives in d_out: dead before k_out fully overwrites it
  float* S1g = out;                 // 16384
  float* S2g = S1g + BH*NCK*DD;     // 16384
  float* SL1 = S2g + BH*NCK*DD;     // 256
  float* SL2 = SL1 + BH*NCK;        // 256

  k_vqk <<<256, 256, 0, stream>>>(X, Wv, bv, Wq, bq, Wk, bk, V, qsg, ksg);
  k_sort<<<BH, 1024, 0, stream>>>(qsg, idxg);
  k_scan<<<BH*NCK, 256, 0, stream>>>(qsg, idxg, V, P1, P2, l1, l2, S1g, S2g, SL1, SL2);
  k_off <<<BH, 256, 0, stream>>>(S1g, S2g, SL1, SL2, Off1, Off2, Loff1, Loff2);
  k_out <<<BH*512, 256, 0, stream>>>(qsg, ksg, P1, P2, Off1, Off2, l1, l2, Loff1, Loff2, out);
}

// Round 3
// 173.002 us; speedup vs baseline: 2.0309x; 1.0475x over previous
//
#include <hip/hip_runtime.h>

// Problem constants (from reference): B=4, N=2048, IN_F=512, HEADS=8, D=64
#define BB   4
#define NN   2048
#define INF  512
#define HH   8
#define DD   64
#define BH   (BB*HH)   // 32
#define NCK  16        // 128-row chunks per (b,h)
#define CKS  128       // chunk size

// ============================================================================
// A[b,h,i,j] = softmax_j( leaky_relu(q_j + k_i) ), H = A @ V.
// exp(leaky(x)) is continuous & piecewise multiplicative:
//   x>=0: e^{q_j} e^{k_i};   x<0: e^{0.01 q_j} e^{0.01 k_i}
// Sort j by q_j per (b,h); prefix sums of e^{q} V and e^{0.01 q} V in sorted
// order turn each output row into: binary search + 2 prefix lookups. O(N·D).
// R2: hierarchical scan (207us serial -> ~20us). R3: k_vqk latency fix.
// ============================================================================

// ---------------- Kernel 1: V = X@Wv + bv ; q,k scalar scores ----------------
// 512 blocks x 16 rows. Thread owns column d for 4 rows; Wv chunk in LDS
// (ds_read_b32, 2-way = free); X via wave-uniform scalar/broadcast loads.
__global__ __launch_bounds__(256) void k_vqk(
    const float* __restrict__ X, const float* __restrict__ Wv, const float* __restrict__ bv,
    const float* __restrict__ Wq, const float* __restrict__ bq,
    const float* __restrict__ Wk, const float* __restrict__ bk,
    float* __restrict__ V, float* __restrict__ qsg, float* __restrict__ ksg)
{
  __shared__ float Ws[128 * DD];    // 32 KB Wv chunk [c][d]
  __shared__ float Vs[16][DD + 1];  // padded
  const int t  = threadIdx.x;
  const int d  = t & 63;
  const int wv = t >> 6;            // wave 0..3 -> rows wv*4..wv*4+3
  const int r0 = blockIdx.x * 16;
  const float* xrow[4];
  #pragma unroll
  for (int r = 0; r < 4; r++) {
    const int row = __builtin_amdgcn_readfirstlane(r0 + wv * 4 + r);
    xrow[r] = X + (size_t)row * INF;
  }
  float acc[4] = {0.f, 0.f, 0.f, 0.f};

  for (int cc = 0; cc < INF; cc += 128) {
    __syncthreads();
    {  // stage 128x64 Wv chunk, coalesced float4
      const float4* src = (const float4*)(Wv + (size_t)cc * DD);
      float4* dst = (float4*)Ws;
      #pragma unroll
      for (int k = 0; k < 8; k++) dst[t + k * 256] = src[t + k * 256];
    }
    __syncthreads();
    for (int c8 = 0; c8 < 128; c8 += 8) {
      float w[8];
      #pragma unroll
      for (int u = 0; u < 8; u++) w[u] = Ws[(c8 + u) * DD + d];
      const int c = cc + c8;
      #pragma unroll
      for (int r = 0; r < 4; r++) {
        const float4 xa = *(const float4*)(xrow[r] + c);
        const float4 xb = *(const float4*)(xrow[r] + c + 4);
        acc[r] += xa.x*w[0] + xa.y*w[1] + xa.z*w[2] + xa.w*w[3]
                + xb.x*w[4] + xb.y*w[5] + xb.z*w[6] + xb.w*w[7];
      }
    }
  }
  __syncthreads();
  const float bvd = bv[d];
  #pragma unroll
  for (int r = 0; r < 4; r++) {
    const int row = wv * 4 + r;
    const float a = acc[r] + bvd;
    V[(size_t)(r0 + row) * DD + d] = a;
    Vs[row][d] = a;
  }
  __syncthreads();
  // q,k: 16 rows x 8 heads x {q,k} = 256 tasks, 1 per thread
  {
    const int row = t >> 4;
    const int h   = t & 7;
    const bool isK = (t & 8) != 0;
    const float* W = isK ? Wk : Wq;
    float a = isK ? bk[h] : bq[h];
    #pragma unroll 8
    for (int dd = 0; dd < DD; dd++) a += Vs[row][dd] * W[dd*HH + h];
    const int grow = r0 + row;
    const int b = grow >> 11, n = grow & (NN - 1);
    (isK ? ksg : qsg)[(b*HH + h) * NN + n] = a;
  }
}

// ---------------- Kernel 2: bitonic sort of q per (b,h), in-place ------------
__global__ __launch_bounds__(1024) void k_sort(
    float* __restrict__ q, unsigned short* __restrict__ idxg)
{
  __shared__ float key[NN];   // 8 KB
  __shared__ int   idx[NN];   // 8 KB
  const int t  = threadIdx.x;
  const int bh = blockIdx.x;
  key[t]        = q[bh*NN + t];        idx[t]        = t;
  key[t + 1024] = q[bh*NN + t + 1024]; idx[t + 1024] = t + 1024;
  __syncthreads();
  for (int size = 2; size <= NN; size <<= 1) {
    for (int stride = size >> 1; stride > 0; stride >>= 1) {
      const int i = ((t & ~(stride - 1)) << 1) | (t & (stride - 1));
      const int j = i + stride;
      const bool up = ((i & size) == 0);
      const float a = key[i], b = key[j];
      if (up ? (a > b) : (a < b)) {
        key[i] = b; key[j] = a;
        const int tmp = idx[i]; idx[i] = idx[j]; idx[j] = tmp;
      }
      __syncthreads();
    }
  }
  q[bh*NN + t]        = key[t];
  q[bh*NN + t + 1024] = key[t + 1024];
  idxg[bh*NN + t]        = (unsigned short)idx[t];
  idxg[bh*NN + t + 1024] = (unsigned short)idx[t + 1024];
}

// -------- Kernel 3: hierarchical scan — chunk-local prefixes + chunk sums ----
// grid: 32 bh x 16 chunks of 128 rows; 256 thr: d=t&63, g=t>>6 owns 32 rows.
__global__ __launch_bounds__(256) void k_scan(
    const float* __restrict__ sq, const unsigned short* __restrict__ idxg,
    const float* __restrict__ V,
    float* __restrict__ P1, float* __restrict__ P2,
    float* __restrict__ l1, float* __restrict__ l2,
    float* __restrict__ S1g, float* __restrict__ S2g,
    float* __restrict__ SL1, float* __restrict__ SL2)
{
  __shared__ float ss1[4][64], ss2[4][64], sl1[4], sl2[4];
  const int t  = threadIdx.x;
  const int bh = blockIdx.x >> 4;
  const int ck = blockIdx.x & 15;
  const int d  = t & 63, g = t >> 6;
  const int r0 = ck*CKS + g*32;
  const float* Vb  = V + (size_t)(bh >> 3) * NN * DD;
  const float* sqb = sq + bh*NN;
  const unsigned short* ib = idxg + bh*NN;
  float a1 = 0.f, a2 = 0.f, s1 = 0.f, s2 = 0.f;
  #pragma unroll 8
  for (int rr = 0; rr < 32; rr++) {
    const int r = r0 + rr;
    const float qv = sqb[r];
    const float e1 = __expf(qv), e2 = __expf(0.01f*qv);
    const float v  = Vb[(size_t)ib[r]*DD + d];
    a1 += e1*v;  a2 += e2*v;  s1 += e1;  s2 += e2;
  }
  ss1[g][d] = a1;  ss2[g][d] = a2;
  if (d == 0) { sl1[g] = s1;  sl2[g] = s2; }
  __syncthreads();
  float o1 = 0.f, o2 = 0.f, lo1 = 0.f, lo2 = 0.f;
  for (int gg = 0; gg < g; gg++) { o1 += ss1[gg][d]; o2 += ss2[gg][d]; lo1 += sl1[gg]; lo2 += sl2[gg]; }
  if (g == 0) {   // chunk totals -> scratch (lives in d_out, dead before k_out)
    S1g[(bh*NCK + ck)*64 + d] = ss1[0][d]+ss1[1][d]+ss1[2][d]+ss1[3][d];
    S2g[(bh*NCK + ck)*64 + d] = ss2[0][d]+ss2[1][d]+ss2[2][d]+ss2[3][d];
    if (d == 0) {
      SL1[bh*NCK + ck] = sl1[0]+sl1[1]+sl1[2]+sl1[3];
      SL2[bh*NCK + ck] = sl2[0]+sl2[1]+sl2[2]+sl2[3];
    }
  }
  // pass 2: store exclusive chunk-local prefixes (V re-load is L2-hot)
  a1 = o1; a2 = o2; s1 = lo1; s2 = lo2;
  float* P1b = P1 + (size_t)bh*NN*DD;
  float* P2b = P2 + (size_t)bh*NN*DD;
  #pragma unroll 8
  for (int rr = 0; rr < 32; rr++) {
    const int r = r0 + rr;
    const float qv = sqb[r];
    const float e1 = __expf(qv), e2 = __expf(0.01f*qv);
    const float v  = Vb[(size_t)ib[r]*DD + d];
    P1b[(size_t)r*DD + d] = a1;
    P2b[(size_t)r*DD + d] = a2;
    if (d == 0) { l1[bh*NN + r] = s1;  l2[bh*NN + r] = s2; }
    a1 += e1*v;  a2 += e2*v;  s1 += e1;  s2 += e2;
  }
}

// ---------- Kernel 4: fp64 scan of the 16 chunk sums -> chunk offsets --------
__global__ __launch_bounds__(256) void k_off(
    const float* __restrict__ S1g, const float* __restrict__ S2g,
    const float* __restrict__ SL1, const float* __restrict__ SL2,
    float* __restrict__ Off1, float* __restrict__ Off2,
    float* __restrict__ Loff1, float* __restrict__ Loff2)
{
  const int bh = blockIdx.x;
  const int t  = threadIdx.x;
  if (t < 128) {
    const int d = t & 63;
    const bool h2 = t >= 64;
    const float* S = h2 ? S2g : S1g;
    float* O = h2 ? Off2 : Off1;
    double a = 0.0;
    for (int ck = 0; ck < NCK; ck++) {
      O[((size_t)bh*(NCK+1) + ck)*64 + d] = (float)a;
      a += (double)S[((size_t)bh*NCK + ck)*64 + d];
    }
    O[((size_t)bh*(NCK+1) + NCK)*64 + d] = (float)a;
  } else if (t == 128 || t == 129) {
    const bool h2 = (t == 129);
    const float* S = h2 ? SL2 : SL1;
    float* O = h2 ? Loff2 : Loff1;
    double a = 0.0;
    for (int ck = 0; ck < NCK; ck++) { O[bh*(NCK+1) + ck] = (float)a; a += (double)S[bh*NCK + ck]; }
    O[bh*(NCK+1) + NCK] = (float)a;
  }
}

// ------- Kernel 5: 64-ary search (2 rounds) + combine + write ----------------
__global__ __launch_bounds__(256) void k_out(
    const float* __restrict__ sq, const float* __restrict__ ksg,
    const float* __restrict__ P1, const float* __restrict__ P2,
    const float* __restrict__ Off1, const float* __restrict__ Off2,
    const float* __restrict__ l1, const float* __restrict__ l2,
    const float* __restrict__ Loff1, const float* __restrict__ Loff2,
    float* __restrict__ out)
{
  const int t  = threadIdx.x;
  const int bh = blockIdx.x >> 9;
  const int i  = ((blockIdx.x & 511) << 2) + (t >> 6);
  const int d  = t & 63;                      // == lane id within wave
  const int b  = bh >> 3, h = bh & 7;
  const float kv = ksg[bh*NN + i];
  const float tt = -kv;
  const float* s = sq + bh*NN;
  // round 1: lane d probes block-of-32 boundary; sorted => ballot contiguous
  const unsigned long long m1 = __ballot(s[d*32 + 31] <= tt);
  const int c1 = __popcll(m1);
  int pos;
  if (c1 == 64) pos = NN;
  else {
    const int bs = c1 << 5;
    const unsigned long long m2 = __ballot(s[bs + (d & 31)] <= tt);
    pos = bs + (__popcll(m2) >> 1);   // both wave halves probe identically
  }
  const float ek  = __expf(kv);
  const float ek2 = __expf(0.01f * kv);
  const size_t base = (size_t)bh * NN * DD;
  const float T1  = Off1[((size_t)bh*(NCK+1) + NCK)*64 + d];
  const float Lt1 = Loff1[bh*(NCK+1) + NCK];
  float p1v, p2v, q1v, q2v;
  if (pos < NN) {   // wave-uniform
    const int ch = pos >> 7;
    p1v = P1[base + (size_t)pos*DD + d] + Off1[((size_t)bh*(NCK+1) + ch)*64 + d];
    p2v = P2[base + (size_t)pos*DD + d] + Off2[((size_t)bh*(NCK+1) + ch)*64 + d];
    q1v = l1[bh*NN + pos] + Loff1[bh*(NCK+1) + ch];
    q2v = l2[bh*NN + pos] + Loff2[bh*(NCK+1) + ch];
  } else {
    p1v = T1;   p2v = Off2[((size_t)bh*(NCK+1) + NCK)*64 + d];
    q1v = Lt1;  q2v = Loff2[bh*(NCK+1) + NCK];
  }
  const float num = ek * (T1 - p1v)  + ek2 * p2v;
  const float den = ek * (Lt1 - q1v) + ek2 * q2v;
  out[((size_t)(b*NN + i)) * (HH*DD) + h*DD + d] = num / den;
}

extern "C" void kernel_launch(void* const* d_in, const int* in_sizes, int n_in,
                              void* d_out, int out_size, void* d_ws, size_t ws_size,
                              hipStream_t stream)
{
  (void)in_sizes; (void)n_in; (void)out_size; (void)ws_size;
  const float* X  = (const float*)d_in[0];
  const float* Wv = (const float*)d_in[1];
  const float* bv = (const float*)d_in[2];
  const float* Wq = (const float*)d_in[3];
  const float* bq = (const float*)d_in[4];
  const float* Wk = (const float*)d_in[5];
  const float* bk = (const float*)d_in[6];
  float* out = (float*)d_out;

  // workspace carve-up (~36.95 MB, <= round-1's proven 37.05 MB)
  float* w = (float*)d_ws;
  float* V     = w;  w += (size_t)BB*NN*DD;        // 524288
  float* qsg   = w;  w += BH*NN;                   // sorted in-place -> sq
  float* ksg   = w;  w += BH*NN;
  float* l1    = w;  w += BH*NN;
  float* l2    = w;  w += BH*NN;
  unsigned short* idxg = (unsigned short*)w;  w += BH*NN/2;   // ushort
  float* Off1  = w;  w += BH*(NCK+1)*DD;           // 34816
  float* Off2  = w;  w += BH*(NCK+1)*DD;
  float* Loff1 = w;  w += BH*(NCK+1);
  float* Loff2 = w;  w += BH*(NCK+1);
  float* P1    = w;  w += (size_t)BH*NN*DD;        // 4194304
  float* P2    = w;  w += (size_t)BH*NN*DD;

  // chunk-sum scratch lives in d_out: dead before k_out fully overwrites it
  float* S1g = out;                 // 32768
  float* S2g = S1g + BH*NCK*DD;     // 32768
  float* SL1 = S2g + BH*NCK*DD;     // 512
  float* SL2 = SL1 + BH*NCK;        // 512

  k_vqk <<<512, 256, 0, stream>>>(X, Wv, bv, Wq, bq, Wk, bk, V, qsg, ksg);
  k_sort<<<BH, 1024, 0, stream>>>(qsg, idxg);
  k_scan<<<BH*NCK, 256, 0, stream>>>(qsg, idxg, V, P1, P2, l1, l2, S1g, S2g, SL1, SL2);
  k_off <<<BH, 256, 0, stream>>>(S1g, S2g, SL1, SL2, Off1, Off2, Loff1, Loff2);
  k_out <<<BH*512, 256, 0, stream>>>(qsg, ksg, P1, P2, Off1, Off2, l1, l2, Loff1, Loff2, out);
}